// Round 1
// baseline (22627.507 us; speedup 1.0000x reference)
//
#include <hip/hip_runtime.h>
#include <stdint.h>
#include <stddef.h>

// Problem dims (fixed)
#define S_LEN 512
#define BATCH 64
#define ISZ   512
#define HID   512
#define NDIR  2

typedef short bf16x8 __attribute__((ext_vector_type(8)));
typedef unsigned short u16x8 __attribute__((ext_vector_type(8)));
typedef float f32x4 __attribute__((ext_vector_type(4)));

// ---- workspace layout (shorts unless noted) ----
// Xb  : [S][4 batch-groups][16*512] bf16, XOR-swizzled 16B units
// hh  : [D][513 slots][4 batch-groups][16*512] bf16, same swizzle (slot 0 = initial_h)
// cnt : [D][4][513] int  (byte region, memset to 0 each call)
#define XB_ELEMS  ((size_t)S_LEN * 4 * 8192)          // 16,777,216 shorts
#define HH_ELEMS  ((size_t)NDIR * 513 * 4 * 8192)     // 33,619,968 shorts
#define CNT_BYTES ((size_t)NDIR * 4 * 513 * 4)        // 16,416 B
#define XB_BYTES  (XB_ELEMS * 2)
#define HH_BYTES  (HH_ELEMS * 2)

__device__ __forceinline__ unsigned short f2bf(float f) {
    // round-to-nearest-even fp32 -> bf16 (inputs finite)
    unsigned int u = __float_as_uint(f);
    u += 0x7fffu + ((u >> 16) & 1u);
    return (unsigned short)(u >> 16);
}

// K1: convert X (S,B,I) fp32 -> swizzled bf16 blocks [t][i][b&15][k-units ^ (b&7)]
__global__ void k_convX(const float* __restrict__ X, unsigned short* __restrict__ Xb) {
    int gu = blockIdx.x * 256 + threadIdx.x;       // 2,097,152 units of 8 elems
    int t   = gu >> 12;                            // 4096 units per timestep
    int rem = gu & 4095;
    int b   = rem >> 6;
    int u   = rem & 63;
    const float* src = X + ((size_t)(t * 64 + b)) * 512 + u * 8;
    float4 a = *(const float4*)(src);
    float4 c = *(const float4*)(src + 4);
    u16x8 o;
    o[0]=f2bf(a.x); o[1]=f2bf(a.y); o[2]=f2bf(a.z); o[3]=f2bf(a.w);
    o[4]=f2bf(c.x); o[5]=f2bf(c.y); o[6]=f2bf(c.z); o[7]=f2bf(c.w);
    int i = b >> 4, br = b & 15;
    size_t off = ((size_t)(t * 4 + i)) * 8192 + (size_t)br * 512 + (size_t)((u ^ (b & 7)) << 3);
    *(u16x8*)(Xb + off) = o;
}

// K2: initial_h (D,B,H) fp32 -> hh slot 0 (swizzled bf16)
__global__ void k_initH(const float* __restrict__ h0, unsigned short* __restrict__ hh) {
    int gu = blockIdx.x * 256 + threadIdx.x;       // 8192 units
    int d   = gu >> 12;
    int rem = gu & 4095;
    int b   = rem >> 6;
    int u   = rem & 63;
    const float* src = h0 + ((size_t)(d * 64 + b)) * 512 + u * 8;
    float4 a = *(const float4*)(src);
    float4 c = *(const float4*)(src + 4);
    u16x8 o;
    o[0]=f2bf(a.x); o[1]=f2bf(a.y); o[2]=f2bf(a.z); o[3]=f2bf(a.w);
    o[4]=f2bf(c.x); o[5]=f2bf(c.y); o[6]=f2bf(c.z); o[7]=f2bf(c.w);
    int i = b >> 4, br = b & 15;
    size_t blk = ((size_t)d * 513 + 0) * 4 + i;
    size_t off = blk * 8192 + (size_t)br * 512 + (size_t)((u ^ (b & 7)) << 3);
    *(u16x8*)(hh + off) = o;
}

// Phase 2: persistent bidirectional LSTM. 256 WGs (= 1/CU), 256 threads.
// blockIdx.x -> d = bx>>7, i = (bx>>5)&3 (batch group of 16), j = bx&31 (16 h-cols).
// Wave w (0..3) = gate w, gate order in g: [i, o, f, c~].
__launch_bounds__(256, 1)
__global__ void k_lstm(const float* __restrict__ W, const float* __restrict__ R,
                       const float* __restrict__ Bb, const int* __restrict__ slen,
                       const float* __restrict__ h0g, const float* __restrict__ c0g,
                       const float* __restrict__ P,
                       const unsigned short* __restrict__ Xb,
                       unsigned short* __restrict__ hh,
                       int* __restrict__ cnt,
                       float* __restrict__ Y) {
    __shared__ __align__(16) unsigned short xbuf[8192];
    __shared__ __align__(16) unsigned short hbuf[8192];
    __shared__ __align__(16) float gbuf[4 * 256];

    const int tid = threadIdx.x;
    const int bx  = blockIdx.x;
    const int d   = bx >> 7;
    const int i   = (bx >> 5) & 3;
    const int j   = bx & 31;
    const int w   = tid >> 6;     // wave = gate
    const int l   = tid & 63;
    const int lr  = l & 15;       // frag row (m for A / n for B)
    const int lq  = l >> 4;       // quad -> k offset lq*8

    // ---- permanent weight fragments (bf16) in registers ----
    bf16x8 Wf[16], Rf[16];
    {
        const int row = w * 512 + j * 16 + lr;  // gate-row 0..2047
        const float* wp = W + ((size_t)(d * 2048 + row)) * 512;
        const float* rp = R + ((size_t)(d * 2048 + row)) * 512;
#pragma unroll
        for (int kc = 0; kc < 16; ++kc) {
            int k0 = kc * 32 + lq * 8;
            float4 a = *(const float4*)(wp + k0);
            float4 b4 = *(const float4*)(wp + k0 + 4);
            bf16x8 f;
            f[0]=(short)f2bf(a.x);  f[1]=(short)f2bf(a.y);  f[2]=(short)f2bf(a.z);  f[3]=(short)f2bf(a.w);
            f[4]=(short)f2bf(b4.x); f[5]=(short)f2bf(b4.y); f[6]=(short)f2bf(b4.z); f[7]=(short)f2bf(b4.w);
            Wf[kc] = f;
            a  = *(const float4*)(rp + k0);
            b4 = *(const float4*)(rp + k0 + 4);
            bf16x8 g;
            g[0]=(short)f2bf(a.x);  g[1]=(short)f2bf(a.y);  g[2]=(short)f2bf(a.z);  g[3]=(short)f2bf(a.w);
            g[4]=(short)f2bf(b4.x); g[5]=(short)f2bf(b4.y); g[6]=(short)f2bf(b4.z); g[7]=(short)f2bf(b4.w);
            Rf[kc] = g;
        }
    }

    // ---- per-thread elementwise constants: thread = (batch row eb, h-col ec) ----
    const int eb = tid >> 4;          // 0..15
    const int ec = tid & 15;          // 0..15
    const int bg = i * 16 + eb;       // global batch
    const int kh = j * 16 + ec;       // global h-col
    const float bias_i = Bb[d * 4096 + 0 * 512 + kh] + Bb[d * 4096 + 2048 + 0 * 512 + kh];
    const float bias_o = Bb[d * 4096 + 1 * 512 + kh] + Bb[d * 4096 + 2048 + 1 * 512 + kh];
    const float bias_f = Bb[d * 4096 + 2 * 512 + kh] + Bb[d * 4096 + 2048 + 2 * 512 + kh];
    const float bias_c = Bb[d * 4096 + 3 * 512 + kh] + Bb[d * 4096 + 2048 + 3 * 512 + kh];
    const float Pi = P[d * 1536 + kh];
    const float Pf = P[d * 1536 + 512 + kh];
    const float Po = P[d * 1536 + 1024 + kh];
    const int   sl  = slen[bg];
    const float h0v = h0g[((size_t)d * 64 + bg) * 512 + kh];
    const float c0v = c0g[((size_t)d * 64 + bg) * 512 + kh];
    float c_state = c0v;

    int* mycnt = cnt + (d * 4 + i) * 513;
    const int rbase = lr * 512;       // LDS row base (shorts)
    const int swz   = lr & 7;

    for (int ts = 0; ts < 512; ++ts) {
        const int t = (d == 0) ? ts : (511 - ts);

        // stage x tile (identity copy of pre-swizzled 16KB block)
        {
            const u16x8* src = (const u16x8*)(Xb + ((size_t)(t * 4 + i)) * 8192);
            u16x8* dst = (u16x8*)xbuf;
#pragma unroll
            for (int s = 0; s < 4; ++s) dst[tid + 256 * s] = src[tid + 256 * s];
        }
        __syncthreads();

        // x-GEMM (overlaps the wait for other producers)
        f32x4 acc = {0.f, 0.f, 0.f, 0.f};
#pragma unroll
        for (int kc = 0; kc < 16; ++kc) {
            int u = (kc * 4 + lq) ^ swz;
            bf16x8 a = *(const bf16x8*)(xbuf + rbase + u * 8);
            acc = __builtin_amdgcn_mfma_f32_16x16x32_bf16(a, Wf[kc], acc, 0, 0, 0);
        }

        // wait for h slot ts (slot 0 pre-filled by k_initH)
        if (ts > 0) {
            if (tid == 0) {
                int iters = 0;
                while (__hip_atomic_load(&mycnt[ts], __ATOMIC_ACQUIRE,
                                         __HIP_MEMORY_SCOPE_AGENT) < 32) {
                    __builtin_amdgcn_s_sleep(2);
                    if (++iters > 2000000) break;   // safety: avoid infinite hang
                }
            }
            __syncthreads();
            __threadfence();   // acquire: make producers' h stores visible to all lanes
        }

        // stage h tile (identity copy, already swizzled in global)
        {
            const u16x8* src = (const u16x8*)(hh + (((size_t)d * 513 + ts) * 4 + i) * 8192);
            u16x8* dst = (u16x8*)hbuf;
#pragma unroll
            for (int s = 0; s < 4; ++s) dst[tid + 256 * s] = src[tid + 256 * s];
        }
        __syncthreads();

        // h-GEMM
#pragma unroll
        for (int kc = 0; kc < 16; ++kc) {
            int u = (kc * 4 + lq) ^ swz;
            bf16x8 a = *(const bf16x8*)(hbuf + rbase + u * 8);
            acc = __builtin_amdgcn_mfma_f32_16x16x32_bf16(a, Rf[kc], acc, 0, 0, 0);
        }

        // exchange gates through LDS: gbuf[gate][b][hc]
#pragma unroll
        for (int r = 0; r < 4; ++r) {
            int b = lq * 4 + r;                    // C/D: row=(lane>>4)*4+reg, col=lane&15
            gbuf[w * 256 + b * 16 + lr] = acc[r];
        }
        __syncthreads();

        // elementwise (one thread per (b, hc))
        {
            float gi = gbuf[0 * 256 + tid] + bias_i;
            float go = gbuf[1 * 256 + tid] + bias_o;
            float gf = gbuf[2 * 256 + tid] + bias_f;
            float gc = gbuf[3 * 256 + tid] + bias_c;
            float c  = c_state;
            float it = 1.f / (1.f + __expf(-(gi + Pi * c)));
            float ft = 1.f / (1.f + __expf(-(gf + Pf * c)));
            float ct = 1.f - 2.f / (__expf(2.f * gc) + 1.f);
            float cn = ft * c + it * ct;
            float ot = 1.f / (1.f + __expf(-(go + Po * cn)));
            float hn = ot * (1.f - 2.f / (__expf(2.f * cn) + 1.f));
            if (t >= sl) { hn = h0v; cn = c0v; }
            c_state = cn;

            // Y (S,D,B,H)
            Y[(((size_t)t * 2 + d) * 64 + bg) * 512 + kh] = hn;
            // h history slot ts+1 (swizzled bf16)
            size_t off = (((size_t)d * 513 + (ts + 1)) * 4 + i) * 8192
                       + (size_t)eb * 512 + (size_t)((((kh >> 3) ^ (eb & 7)) << 3) + (kh & 7));
            hh[off] = f2bf(hn);
            if (ts == 511) {
                Y[(size_t)33554432 + ((size_t)d * 64 + bg) * 512 + kh] = hn;   // Y_h
                Y[(size_t)33619968 + ((size_t)d * 64 + bg) * 512 + kh] = cn;   // Y_c
            }
        }

        __threadfence();        // release: each thread drains/publishes its own stores
        __syncthreads();
        if (tid == 0) {
            __hip_atomic_fetch_add(&mycnt[ts + 1], 1, __ATOMIC_RELEASE,
                                   __HIP_MEMORY_SCOPE_AGENT);
        }
    }
}

extern "C" void kernel_launch(void* const* d_in, const int* in_sizes, int n_in,
                              void* d_out, int out_size, void* d_ws, size_t ws_size,
                              hipStream_t stream) {
    const float* X  = (const float*)d_in[0];
    const float* W  = (const float*)d_in[1];
    const float* R  = (const float*)d_in[2];
    const float* Bb = (const float*)d_in[3];
    const int*   sl = (const int*)d_in[4];
    const float* h0 = (const float*)d_in[5];
    const float* c0 = (const float*)d_in[6];
    const float* P  = (const float*)d_in[7];
    float* Y = (float*)d_out;

    unsigned short* Xb  = (unsigned short*)d_ws;
    unsigned short* hh  = (unsigned short*)((char*)d_ws + XB_BYTES);
    int*            cnt = (int*)((char*)d_ws + XB_BYTES + HH_BYTES);

    // zero sync counters (ws is poisoned before every timed call)
    hipMemsetAsync(cnt, 0, CNT_BYTES, stream);

    // K1: X -> swizzled bf16
    k_convX<<<8192, 256, 0, stream>>>(X, Xb);
    // K2: initial_h -> hh slot 0
    k_initH<<<32, 256, 0, stream>>>(h0, hh);
    // Phase 2: persistent recurrence (256 WGs, one per CU)
    k_lstm<<<256, 256, 0, stream>>>(W, R, Bb, sl, h0, c0, P, Xb, hh, cnt, Y);
}

// Round 2
// 4083.579 us; speedup vs baseline: 5.5411x; 5.5411x over previous
//
#include <hip/hip_runtime.h>
#include <stdint.h>
#include <stddef.h>

// Problem dims (fixed)
#define S_LEN 512
#define BATCH 64
#define ISZ   512
#define HID   512
#define NDIR  2

typedef short bf16x8 __attribute__((ext_vector_type(8)));
typedef unsigned short u16x8 __attribute__((ext_vector_type(8)));
typedef float f32x4 __attribute__((ext_vector_type(4)));

// ---- workspace layout (shorts unless noted) ----
// Xb  : [S][4 batch-groups][16*512] bf16, XOR-swizzled 16B units
// hh  : [D][513 slots][4 batch-groups][16*512] bf16, same swizzle (slot 0 = initial_h)
// cnt : [D][4][513] int  (byte region, memset to 0 each call)
#define XB_ELEMS  ((size_t)S_LEN * 4 * 8192)          // 16,777,216 shorts
#define HH_ELEMS  ((size_t)NDIR * 513 * 4 * 8192)     // 33,619,968 shorts
#define CNT_BYTES ((size_t)NDIR * 4 * 513 * 4)        // 16,416 B
#define XB_BYTES  (XB_ELEMS * 2)
#define HH_BYTES  (HH_ELEMS * 2)

__device__ __forceinline__ unsigned short f2bf(float f) {
    // round-to-nearest-even fp32 -> bf16 (inputs finite)
    unsigned int u = __float_as_uint(f);
    u += 0x7fffu + ((u >> 16) & 1u);
    return (unsigned short)(u >> 16);
}

// K1: convert X (S,B,I) fp32 -> swizzled bf16 blocks [t][i][b&15][k-units ^ (b&7)]
__global__ void k_convX(const float* __restrict__ X, unsigned short* __restrict__ Xb) {
    int gu = blockIdx.x * 256 + threadIdx.x;       // 2,097,152 units of 8 elems
    int t   = gu >> 12;                            // 4096 units per timestep
    int rem = gu & 4095;
    int b   = rem >> 6;
    int u   = rem & 63;
    const float* src = X + ((size_t)(t * 64 + b)) * 512 + u * 8;
    float4 a = *(const float4*)(src);
    float4 c = *(const float4*)(src + 4);
    u16x8 o;
    o[0]=f2bf(a.x); o[1]=f2bf(a.y); o[2]=f2bf(a.z); o[3]=f2bf(a.w);
    o[4]=f2bf(c.x); o[5]=f2bf(c.y); o[6]=f2bf(c.z); o[7]=f2bf(c.w);
    int i = b >> 4, br = b & 15;
    size_t off = ((size_t)(t * 4 + i)) * 8192 + (size_t)br * 512 + (size_t)((u ^ (b & 7)) << 3);
    *(u16x8*)(Xb + off) = o;
}

// K2: initial_h (D,B,H) fp32 -> hh slot 0 (swizzled bf16)
__global__ void k_initH(const float* __restrict__ h0, unsigned short* __restrict__ hh) {
    int gu = blockIdx.x * 256 + threadIdx.x;       // 8192 units
    int d   = gu >> 12;
    int rem = gu & 4095;
    int b   = rem >> 6;
    int u   = rem & 63;
    const float* src = h0 + ((size_t)(d * 64 + b)) * 512 + u * 8;
    float4 a = *(const float4*)(src);
    float4 c = *(const float4*)(src + 4);
    u16x8 o;
    o[0]=f2bf(a.x); o[1]=f2bf(a.y); o[2]=f2bf(a.z); o[3]=f2bf(a.w);
    o[4]=f2bf(c.x); o[5]=f2bf(c.y); o[6]=f2bf(c.z); o[7]=f2bf(c.w);
    int i = b >> 4, br = b & 15;
    size_t blk = ((size_t)d * 513 + 0) * 4 + i;
    size_t off = blk * 8192 + (size_t)br * 512 + (size_t)((u ^ (b & 7)) << 3);
    *(u16x8*)(hh + off) = o;
}

// Phase 2: persistent bidirectional LSTM. 256 WGs (= 1/CU), 256 threads.
// blockIdx.x -> d = bx>>7, i = (bx>>5)&3 (batch group of 16), j = bx&31 (16 h-cols).
// Wave w (0..3) = gate w, gate order: [i, o, f, c~].
// Sync design: ALL cross-block traffic (h tiles, flags) uses relaxed agent-scope
// atomics -> sc0 sc1 (bypass L1/L2, coherent at LLC). NO acquire/release fences
// anywhere in the loop => zero buffer_inv / buffer_wbl2 cache maintenance.
// Ordering: __syncthreads drains vmcnt(0) (stores reach LLC) before the flag add.
__launch_bounds__(256, 1)
__global__ void k_lstm(const float* __restrict__ W, const float* __restrict__ R,
                       const float* __restrict__ Bb, const int* __restrict__ slen,
                       const float* __restrict__ h0g, const float* __restrict__ c0g,
                       const float* __restrict__ P,
                       const unsigned short* __restrict__ Xb,
                       unsigned short* __restrict__ hh,
                       int* __restrict__ cnt,
                       float* __restrict__ Y) {
    __shared__ __align__(16) float gbuf[4 * 256];
    __shared__ __align__(4) unsigned short hexch[256];

    const int tid = threadIdx.x;
    const int bx  = blockIdx.x;
    const int d   = bx >> 7;
    const int i   = (bx >> 5) & 3;
    const int j   = bx & 31;
    const int w   = tid >> 6;     // wave = gate
    const int l   = tid & 63;
    const int lr  = l & 15;       // frag row (m for A / n for B)
    const int lq  = l >> 4;       // quad -> k offset lq*8

    // ---- permanent weight fragments (bf16) in registers ----
    bf16x8 Wf[16], Rf[16];
    {
        const int row = w * 512 + j * 16 + lr;  // gate-row 0..2047
        const float* wp = W + ((size_t)(d * 2048 + row)) * 512;
        const float* rp = R + ((size_t)(d * 2048 + row)) * 512;
#pragma unroll
        for (int kc = 0; kc < 16; ++kc) {
            int k0 = kc * 32 + lq * 8;
            float4 a = *(const float4*)(wp + k0);
            float4 b4 = *(const float4*)(wp + k0 + 4);
            bf16x8 f;
            f[0]=(short)f2bf(a.x);  f[1]=(short)f2bf(a.y);  f[2]=(short)f2bf(a.z);  f[3]=(short)f2bf(a.w);
            f[4]=(short)f2bf(b4.x); f[5]=(short)f2bf(b4.y); f[6]=(short)f2bf(b4.z); f[7]=(short)f2bf(b4.w);
            Wf[kc] = f;
            a  = *(const float4*)(rp + k0);
            b4 = *(const float4*)(rp + k0 + 4);
            bf16x8 g;
            g[0]=(short)f2bf(a.x);  g[1]=(short)f2bf(a.y);  g[2]=(short)f2bf(a.z);  g[3]=(short)f2bf(a.w);
            g[4]=(short)f2bf(b4.x); g[5]=(short)f2bf(b4.y); g[6]=(short)f2bf(b4.z); g[7]=(short)f2bf(b4.w);
            Rf[kc] = g;
        }
    }

    // ---- per-thread elementwise constants: thread = (batch row eb, h-col ec) ----
    const int eb = tid >> 4;          // 0..15
    const int ec = tid & 15;          // 0..15
    const int bg = i * 16 + eb;       // global batch
    const int kh = j * 16 + ec;       // global h-col
    const float bias_i = Bb[d * 4096 + 0 * 512 + kh] + Bb[d * 4096 + 2048 + 0 * 512 + kh];
    const float bias_o = Bb[d * 4096 + 1 * 512 + kh] + Bb[d * 4096 + 2048 + 1 * 512 + kh];
    const float bias_f = Bb[d * 4096 + 2 * 512 + kh] + Bb[d * 4096 + 2048 + 2 * 512 + kh];
    const float bias_c = Bb[d * 4096 + 3 * 512 + kh] + Bb[d * 4096 + 2048 + 3 * 512 + kh];
    const float Pi = P[d * 1536 + kh];
    const float Pf = P[d * 1536 + 512 + kh];
    const float Po = P[d * 1536 + 1024 + kh];
    const int   sl  = slen[bg];
    const float h0v = h0g[((size_t)d * 64 + bg) * 512 + kh];
    const float c0v = c0g[((size_t)d * 64 + bg) * 512 + kh];
    float c_state = c0v;

    int* mycnt = cnt + (d * 4 + i) * 513;
    const int rbase = lr * 512;       // row base (shorts) in a tile block
    const int swz   = lr & 7;

    // pack-store constants (threads 0..127): one uint = 2 adjacent h-cols
    const int peb = tid >> 3;         // batch row 0..15
    const int pm  = tid & 7;          // uint-pair index within row
    const size_t puo = (size_t)peb * 256
                     + (size_t)((((2 * j + (pm >> 2)) ^ (peb & 7)) << 2) + (pm & 3));

    for (int ts = 0; ts < 512; ++ts) {
        const int t = (d == 0) ? ts : (511 - ts);

        // x-GEMM straight from global (cached loads; layout == fragment layout).
        // Runs before the poll -> overlaps waiting on producers.
        f32x4 acc = {0.f, 0.f, 0.f, 0.f};
        {
            const unsigned short* xsrc = Xb + ((size_t)(t * 4 + i)) * 8192;
#pragma unroll
            for (int kc = 0; kc < 16; ++kc) {
                int u = (kc * 4 + lq) ^ swz;
                bf16x8 a = *(const bf16x8*)(xsrc + rbase + u * 8);
                acc = __builtin_amdgcn_mfma_f32_16x16x32_bf16(a, Wf[kc], acc, 0, 0, 0);
            }
        }

        // wait for h slot ts (slot 0 pre-filled by k_initH).
        // RELAXED poll: single sc0sc1 dword load per iteration, no cache invalidation.
        if (ts > 0) {
            if (tid == 0) {
                int iters = 0;
                while (__hip_atomic_load(&mycnt[ts], __ATOMIC_RELAXED,
                                         __HIP_MEMORY_SCOPE_AGENT) < 32) {
                    __builtin_amdgcn_s_sleep(1);
                    if (++iters > 4000000) break;   // safety: avoid infinite hang
                }
            }
            __syncthreads();
        }

        // h fragments: relaxed agent-scope dword loads (sc0 sc1 -> read LLC, skip
        // possibly-stale L1/L2). Issue all 64, then convert+MFMA.
        {
            const unsigned int* hsrc =
                (const unsigned int*)(hh + (((size_t)d * 513 + ts) * 4 + i) * 8192);
            unsigned int hv[64];
#pragma unroll
            for (int kc = 0; kc < 16; ++kc) {
                int u = (kc * 4 + lq) ^ swz;
                const unsigned int* p = hsrc + (lr * 256 + u * 4);
                hv[kc * 4 + 0] = __hip_atomic_load(p + 0, __ATOMIC_RELAXED, __HIP_MEMORY_SCOPE_AGENT);
                hv[kc * 4 + 1] = __hip_atomic_load(p + 1, __ATOMIC_RELAXED, __HIP_MEMORY_SCOPE_AGENT);
                hv[kc * 4 + 2] = __hip_atomic_load(p + 2, __ATOMIC_RELAXED, __HIP_MEMORY_SCOPE_AGENT);
                hv[kc * 4 + 3] = __hip_atomic_load(p + 3, __ATOMIC_RELAXED, __HIP_MEMORY_SCOPE_AGENT);
            }
#pragma unroll
            for (int kc = 0; kc < 16; ++kc) {
                union { unsigned int u[4]; bf16x8 v; } cvt;
                cvt.u[0] = hv[kc * 4 + 0];
                cvt.u[1] = hv[kc * 4 + 1];
                cvt.u[2] = hv[kc * 4 + 2];
                cvt.u[3] = hv[kc * 4 + 3];
                acc = __builtin_amdgcn_mfma_f32_16x16x32_bf16(cvt.v, Rf[kc], acc, 0, 0, 0);
            }
        }

        // exchange gates through LDS: gbuf[gate][b][hc]
#pragma unroll
        for (int r = 0; r < 4; ++r) {
            int b = lq * 4 + r;                    // C/D: row=(lane>>4)*4+reg, col=lane&15
            gbuf[w * 256 + b * 16 + lr] = acc[r];
        }
        __syncthreads();

        // elementwise (one thread per (b, hc))
        float hn, cn;
        {
            float gi = gbuf[0 * 256 + tid] + bias_i;
            float go = gbuf[1 * 256 + tid] + bias_o;
            float gf = gbuf[2 * 256 + tid] + bias_f;
            float gc = gbuf[3 * 256 + tid] + bias_c;
            float c  = c_state;
            float it = 1.f / (1.f + __expf(-(gi + Pi * c)));
            float ft = 1.f / (1.f + __expf(-(gf + Pf * c)));
            float ct = 1.f - 2.f / (__expf(2.f * gc) + 1.f);
            cn = ft * c + it * ct;
            float ot = 1.f / (1.f + __expf(-(go + Po * cn)));
            hn = ot * (1.f - 2.f / (__expf(2.f * cn) + 1.f));
            if (t >= sl) { hn = h0v; cn = c0v; }
            c_state = cn;

            // Y (S,D,B,H) — plain cached stores (visibility via end-of-kernel flush)
            Y[(((size_t)t * 2 + d) * 64 + bg) * 512 + kh] = hn;
            if (ts == 511) {
                Y[(size_t)33554432 + ((size_t)d * 64 + bg) * 512 + kh] = hn;   // Y_h
                Y[(size_t)33619968 + ((size_t)d * 64 + bg) * 512 + kh] = cn;   // Y_c
            }
            hexch[tid] = f2bf(hn);
        }
        __syncthreads();

        // publish h slot ts+1: threads 0..127 pack 2 bf16 -> uint, relaxed
        // agent-scope store (sc0 sc1 -> write-through to LLC).
        if (tid < 128) {
            unsigned int v = ((const unsigned int*)hexch)[tid];
            unsigned int* hdst =
                (unsigned int*)(hh + (((size_t)d * 513 + (ts + 1)) * 4 + i) * 8192);
            __hip_atomic_store(hdst + puo, v, __ATOMIC_RELAXED, __HIP_MEMORY_SCOPE_AGENT);
        }
        // drain own stores to the coherence point, then block-wide barrier
        asm volatile("s_waitcnt vmcnt(0)" ::: "memory");
        __syncthreads();
        if (tid == 0) {
            __hip_atomic_fetch_add(&mycnt[ts + 1], 1, __ATOMIC_RELAXED,
                                   __HIP_MEMORY_SCOPE_AGENT);
        }
    }
}

extern "C" void kernel_launch(void* const* d_in, const int* in_sizes, int n_in,
                              void* d_out, int out_size, void* d_ws, size_t ws_size,
                              hipStream_t stream) {
    const float* X  = (const float*)d_in[0];
    const float* W  = (const float*)d_in[1];
    const float* R  = (const float*)d_in[2];
    const float* Bb = (const float*)d_in[3];
    const int*   sl = (const int*)d_in[4];
    const float* h0 = (const float*)d_in[5];
    const float* c0 = (const float*)d_in[6];
    const float* P  = (const float*)d_in[7];
    float* Y = (float*)d_out;

    unsigned short* Xb  = (unsigned short*)d_ws;
    unsigned short* hh  = (unsigned short*)((char*)d_ws + XB_BYTES);
    int*            cnt = (int*)((char*)d_ws + XB_BYTES + HH_BYTES);

    // zero sync counters (ws is poisoned before every timed call)
    hipMemsetAsync(cnt, 0, CNT_BYTES, stream);

    // K1: X -> swizzled bf16
    k_convX<<<8192, 256, 0, stream>>>(X, Xb);
    // K2: initial_h -> hh slot 0
    k_initH<<<32, 256, 0, stream>>>(h0, hh);
    // Phase 2: persistent recurrence (256 WGs, one per CU)
    k_lstm<<<256, 256, 0, stream>>>(W, R, Bb, sl, h0, c0, P, Xb, hh, cnt, Y);
}